// Round 3
// baseline (6337.878 us; speedup 1.0000x reference)
//
#include <hip/hip_runtime.h>
#include <stdint.h>

// Problem dims
#define Md 50
#define Kd 50
#define Vd 200
#define Ad 64
#define Bd 512
#define Sd 1024

__device__ __forceinline__ float fast_tanh(float x) {
    float e = __expf(2.f * x);
    return 1.f - 2.f / (e + 1.f);
}

__device__ __forceinline__ float sigmoidf_(float x) {
    return 1.f / (1.f + __expf(-x));
}

// 256 blocks x 512 threads; block handles batch elements 2*blk and 2*blk+1
// Thread roles:
//   hb = tid>>8 (batch half), mv = tid&255 (memory column v, active <200)
//   wv = tid>>1, wh = tid&1  (We/Wa row ownership for stage 5)
//   a4 = ((tid>>6)<<3)|(tid&7), c4 = (tid&63)>>3  (Wr slice for stage 4)
__global__ __launch_bounds__(512, 2)
void agm_kernel(const float* __restrict__ q_in,    // (B,S,K)
                const float* __restrict__ a_in,    // (B,S,A)
                const float* __restrict__ mem_in,  // (B,M,V)
                const float* __restrict__ key_in,  // (M,K)
                const float* __restrict__ Wc_in,   // (K,K)
                const float* __restrict__ bc_in,   // (K)
                const float* __restrict__ Wr_in,   // (A,V)
                const float* __restrict__ br_in,   // (A)
                const float* __restrict__ We_in,   // (V,2A)
                const float* __restrict__ be_in,   // (V)
                const float* __restrict__ Wa_in,   // (V,2A)
                const float* __restrict__ ba_in,   // (V)
                float* __restrict__ rc_out,        // (B,S,A)
                float* __restrict__ mem_out,       // (B,M,V)
                float* __restrict__ w_out)         // (B,S,M)
{
    __shared__ float sWcT[Kd * Kd];            // fp32: WcT[k][i] = Wc[i][k]
    __shared__ float sKeyT[Kd * Md];           // fp32: keyT[k][m] = key[m][k]
    __shared__ float sbc[Kd], sbr[Ad], sbe[Vd], sba[Vd];
    __shared__ float sq[2][Kd];
    __shared__ __align__(16) float swi[2][128];   // [0:64)=a_t, [64:128)=rc
    __shared__ float sck[2][64];
    __shared__ float sw[2][64];
    __shared__ float srcv[2][Vd];
    __shared__ float ser[2][Vd], sad[2][Vd];

    const int tid = threadIdx.x;
    const int blk = blockIdx.x;

    const int hb = tid >> 8;     // batch half (0/1)
    const int mv = tid & 255;    // memory column
    const int bidx = blk * 2 + hb;

    // ---------- one-time preload of shared weights (fp32) ----------
    for (int idx = tid; idx < Kd * Kd; idx += 512) {
        int i = idx / Kd, k = idx % Kd;
        sWcT[k * Kd + i] = Wc_in[idx];
        sKeyT[k * Md + i] = key_in[idx];
    }
    if (tid < Kd) sbc[tid] = bc_in[tid];
    if (tid < Ad) sbr[tid] = br_in[tid];
    if (tid < Vd) { sbe[tid] = be_in[tid]; sba[tid] = ba_in[tid]; }

    // ---------- register-resident Wr slice (stage 4) ----------
    const int a4 = ((tid >> 6) << 3) | (tid & 7);   // a in [0,64)
    const int c4 = (tid & 63) >> 3;                  // v-chunk in [0,8)
    float WrS[25];
    #pragma unroll
    for (int j = 0; j < 25; ++j)
        WrS[j] = Wr_in[a4 * Vd + c4 * 25 + j];

    // ---------- register-resident We/Wa chunks (full fp32) ----------
    const int wv = tid >> 1;   // row v in [0,256)
    const int wh = tid & 1;    // which 64-wide half of the 128 k's
    float WeC[64], WaC[64];
    if (wv < Vd) {
        const float4* wep = (const float4*)(We_in + wv * 128 + wh * 64);
        const float4* wap = (const float4*)(Wa_in + wv * 128 + wh * 64);
        #pragma unroll
        for (int c = 0; c < 16; ++c) {
            float4 ue = wep[c];
            float4 ua = wap[c];
            WeC[4*c+0] = ue.x; WeC[4*c+1] = ue.y;
            WeC[4*c+2] = ue.z; WeC[4*c+3] = ue.w;
            WaC[4*c+0] = ua.x; WaC[4*c+1] = ua.y;
            WaC[4*c+2] = ua.z; WaC[4*c+3] = ua.w;
        }
    } else {
        #pragma unroll
        for (int j = 0; j < 64; ++j) { WeC[j] = 0.f; WaC[j] = 0.f; }
    }

    // ---------- register-resident memory column ----------
    float memcol[Md];
    if (mv < Vd) {
        #pragma unroll
        for (int m = 0; m < Md; ++m)
            memcol[m] = mem_in[(size_t)bidx * Md * Vd + m * Vd + mv];
    } else {
        #pragma unroll
        for (int m = 0; m < Md; ++m) memcol[m] = 0.f;
    }

    // ---------- q/a prefetch roles ----------
    const bool is_q = (tid < 100);
    const int qhb = tid / 50, qk = tid % 50;           // valid when is_q
    const bool is_a = (tid >= 256 && tid < 384);
    const int ahb = (tid - 256) >> 6, aj = tid & 63;   // valid when is_a

    float qreg = 0.f, areg = 0.f;
    if (is_q) qreg = q_in[(size_t)(blk * 2 + qhb) * Sd * Kd + qk];
    if (is_a) areg = a_in[(size_t)(blk * 2 + ahb) * Sd * Ad + aj];

    // ---------- main sequential scan ----------
    for (int t = 0; t < Sd; ++t) {
        // stage 0: commit prefetched q_t / a_t to LDS
        if (is_q) sq[qhb][qk] = qreg;
        if (is_a) swi[ahb][aj] = areg;
        __syncthreads();  // B0

        // prefetch t+1 (consumed next iteration -> latency hidden)
        if (t + 1 < Sd) {
            if (is_q) qreg = q_in[(size_t)(blk * 2 + qhb) * Sd * Kd + (t + 1) * Kd + qk];
            if (is_a) areg = a_in[(size_t)(blk * 2 + ahb) * Sd * Ad + (t + 1) * Ad + aj];
        }

        // stage 1: ck = tanh(q @ Wc^T + bc)
        if (mv < Kd) {
            float acc = sbc[mv];
            for (int k = 0; k < Kd; ++k)
                acc = fmaf(sq[hb][k], sWcT[k * Kd + mv], acc);
            sck[hb][mv] = fast_tanh(acc);
        }
        __syncthreads();  // B1

        // stage 2: logits + softmax (one wave per batch half)
        if (mv < 64) {
            int m = mv;
            float lg = -1e30f;
            if (m < Md) {
                lg = 0.f;
                for (int k = 0; k < Kd; ++k)
                    lg = fmaf(sck[hb][k], sKeyT[k * Md + m], lg);
            }
            float mx = lg;
            #pragma unroll
            for (int off = 32; off > 0; off >>= 1)
                mx = fmaxf(mx, __shfl_xor(mx, off));
            float e = (m < Md) ? __expf(lg - mx) : 0.f;
            float sm = e;
            #pragma unroll
            for (int off = 32; off > 0; off >>= 1)
                sm += __shfl_xor(sm, off);
            if (m < Md) sw[hb][m] = e / sm;
        }
        __syncthreads();  // B2

        // stage 3: rc_v[v] = sum_m w[m]*mem[m][v]; also emit w output
        if (mv < Vd) {
            float acc = 0.f;
            #pragma unroll
            for (int m = 0; m < Md; ++m)
                acc = fmaf(sw[hb][m], memcol[m], acc);
            srcv[hb][mv] = acc;
        }
        if (mv < Md) {
            w_out[(size_t)bidx * Sd * Md + (size_t)t * Md + mv] = sw[hb][mv];
        }
        __syncthreads();  // B3

        // stage 4: rc[a] = sum_v srcv[v]*Wr[a][v] + br[a]  (both hb/thread,
        // register Wr slice, in-wave reduction over 8 c-chunks)
        {
            float p0 = 0.f, p1 = 0.f;
            #pragma unroll
            for (int j = 0; j < 25; ++j) {
                int v = c4 * 25 + j;
                p0 = fmaf(srcv[0][v], WrS[j], p0);
                p1 = fmaf(srcv[1][v], WrS[j], p1);
            }
            #pragma unroll
            for (int off = 8; off < 64; off <<= 1) {
                p0 += __shfl_xor(p0, off);
                p1 += __shfl_xor(p1, off);
            }
            if ((tid & 63) < 8) {
                float rc0 = p0 + sbr[a4];
                float rc1 = p1 + sbr[a4];
                swi[0][64 + a4] = rc0;
                swi[1][64 + a4] = rc1;
                rc_out[(size_t)(blk * 2 + 0) * Sd * Ad + (size_t)t * Ad + a4] = rc0;
                rc_out[(size_t)(blk * 2 + 1) * Sd * Ad + (size_t)t * Ad + a4] = rc1;
            }
        }
        __syncthreads();  // B4

        if (t < Sd - 1) {
            // stage 5: erase/add dots (each thread: 64-wide chunk, both batches)
            float pe0 = 0.f, pa0 = 0.f, pe1 = 0.f, pa1 = 0.f;
            {
                const float4* w0p = (const float4*)&swi[0][wh * 64];
                const float4* w1p = (const float4*)&swi[1][wh * 64];
                #pragma unroll
                for (int j4 = 0; j4 < 16; ++j4) {
                    float4 x0 = w0p[j4];
                    float4 x1 = w1p[j4];
                    pe0 = fmaf(x0.x, WeC[4*j4+0], pe0);
                    pe0 = fmaf(x0.y, WeC[4*j4+1], pe0);
                    pe0 = fmaf(x0.z, WeC[4*j4+2], pe0);
                    pe0 = fmaf(x0.w, WeC[4*j4+3], pe0);
                    pa0 = fmaf(x0.x, WaC[4*j4+0], pa0);
                    pa0 = fmaf(x0.y, WaC[4*j4+1], pa0);
                    pa0 = fmaf(x0.z, WaC[4*j4+2], pa0);
                    pa0 = fmaf(x0.w, WaC[4*j4+3], pa0);
                    pe1 = fmaf(x1.x, WeC[4*j4+0], pe1);
                    pe1 = fmaf(x1.y, WeC[4*j4+1], pe1);
                    pe1 = fmaf(x1.z, WeC[4*j4+2], pe1);
                    pe1 = fmaf(x1.w, WeC[4*j4+3], pe1);
                    pa1 = fmaf(x1.x, WaC[4*j4+0], pa1);
                    pa1 = fmaf(x1.y, WaC[4*j4+1], pa1);
                    pa1 = fmaf(x1.z, WaC[4*j4+2], pa1);
                    pa1 = fmaf(x1.w, WaC[4*j4+3], pa1);
                }
            }
            // combine the two 64-wide halves (adjacent lanes)
            pe0 += __shfl_xor(pe0, 1);
            pa0 += __shfl_xor(pa0, 1);
            pe1 += __shfl_xor(pe1, 1);
            pa1 += __shfl_xor(pa1, 1);
            if (wh == 0 && wv < Vd) {
                ser[0][wv] = sigmoidf_(pe0 + sbe[wv]);
                sad[0][wv] = fast_tanh(pa0 + sba[wv]);
                ser[1][wv] = sigmoidf_(pe1 + sbe[wv]);
                sad[1][wv] = fast_tanh(pa1 + sba[wv]);
            }
            __syncthreads();  // B5

            // stage 6: in-register memory update
            // mem_new = mem + w*(add - erase*mem)   (2 FMA per row)
            if (mv < Vd) {
                float ev = ser[hb][mv], av = sad[hb][mv];
                #pragma unroll
                for (int m = 0; m < Md; ++m) {
                    float wm = sw[hb][m];
                    float inner = fmaf(-ev, memcol[m], av);
                    memcol[m] = fmaf(wm, inner, memcol[m]);
                }
            }
        }
    }

    // ---------- final memory store ----------
    if (mv < Vd) {
        #pragma unroll
        for (int m = 0; m < Md; ++m)
            mem_out[(size_t)bidx * Md * Vd + m * Vd + mv] = memcol[m];
    }
}

extern "C" void kernel_launch(void* const* d_in, const int* in_sizes, int n_in,
                              void* d_out, int out_size, void* d_ws, size_t ws_size,
                              hipStream_t stream) {
    const float* q   = (const float*)d_in[0];
    const float* a   = (const float*)d_in[1];
    const float* mem = (const float*)d_in[2];
    const float* key = (const float*)d_in[3];
    const float* Wc  = (const float*)d_in[4];
    const float* bc  = (const float*)d_in[5];
    const float* Wr  = (const float*)d_in[6];
    const float* br  = (const float*)d_in[7];
    const float* We  = (const float*)d_in[8];
    const float* be  = (const float*)d_in[9];
    const float* Wa  = (const float*)d_in[10];
    const float* ba  = (const float*)d_in[11];

    float* out = (float*)d_out;
    float* rc_out  = out;                                   // (B,S,A)
    float* mem_out = rc_out + (size_t)Bd * Sd * Ad;         // (B,M,V)
    float* w_out   = mem_out + (size_t)Bd * Md * Vd;        // (B,S,M)

    hipLaunchKernelGGL(agm_kernel, dim3(256), dim3(512), 0, stream,
                       q, a, mem, key, Wc, bc, Wr, br, We, be, Wa, ba,
                       rc_out, mem_out, w_out);
}